// Round 7
// baseline (269.609 us; speedup 1.0000x reference)
//
#include <hip/hip_runtime.h>

// Rainfusion blockwise sparse attention. f32 in/out; fp16 MFMA inside.
// Fixed-m softmax (m=0). R7: flash at 4 wg/CU — P buffer aliased into Ks (3rd
// barrier between QK and P-write), LDS 46.6->36.3 KB; heavy tasks split 4x9kb
// (18 tiles); grid 864 with slot-aware task permutation (c=b&255 CU, s=b>>8 slot,
// h=c&7) balancing heavies across CUs. Combine = separate kernel, 4 partials.
// R6 ticket/fence fold REVERTED (L2-writeback fences slowed whole kernel 68%).

typedef __attribute__((ext_vector_type(8))) _Float16 half8;
typedef __attribute__((ext_vector_type(4))) _Float16 half4;
typedef __attribute__((ext_vector_type(2))) _Float16 half2v;
typedef __attribute__((ext_vector_type(4))) float float4v;

#define KROW 136   // shorts per K row: 128 dims + 8 pad
#define VROW 72    // shorts per V^T row: 64 toks + 8 pad (144B rows, 16B-aligned)
#define VSROW 138  // prep-local V staging stride (conflict-free transpose reads)
#define PPROW 40   // shorts per P row: 32 toks + 8 pad (80B rows, 16B-aligned)

__device__ __forceinline__ int orig_pos(int j) {
    if (j >= 3840) return (j < 4224) ? (j - 3840) : j;
    int blk = j >> 7;
    int r   = j & 127;
    int f   = blk / 6;
    int rem = blk - f * 6;
    int b2  = rem / 3;
    int e   = rem - b2 * 3;
    int a   = r >> 6;
    int c   = (r >> 3) & 7;
    int g   = r & 7;
    return 384 + (f * 2 + a) * 384 + (b2 * 8 + c) * 24 + e * 8 + g;
}

__device__ __forceinline__ void cp16(const void* g, void* l) {
    __builtin_amdgcn_global_load_lds((const __attribute__((address_space(1))) void*)g,
                                     (__attribute__((address_space(3))) void*)l, 16, 0, 0);
}

// ---------------- prep: grid 864. bx<576: conv+transpose+pooled-K. bx>=576: pooled-Q. ----------------
__global__ __launch_bounds__(256) void prep_kernel(const float* __restrict__ q,
                                                   const float* __restrict__ k,
                                                   const float* __restrict__ v,
                                                   short* __restrict__ Kc,
                                                   unsigned* __restrict__ Vt32,
                                                   float* __restrict__ qp,
                                                   float* __restrict__ kpart) {
    __shared__ __align__(16) short KsL[64 * KROW];   // 17408 B (mirrors global Kc layout)
    __shared__ short VsL[64 * VSROW];                // 17664 B
    __shared__ float Rs[32 * 128];                   // 16384 B
    int bx  = blockIdx.x;
    int tid = threadIdx.x;

    if (bx < 576) {  // conv: K/V fp16 tiles + pooled-K partials
        int sub = bx & 1;
        int kb  = (bx >> 1) % 36;
        int h   = bx / 72;

        int lr  = tid >> 3;            // row group 0..31
        int ld4 = (tid & 7) << 2;      // float offset 0,4,..,28

        float ksum[16];
#pragma unroll
        for (int i = 0; i < 16; ++i) ksum[i] = 0.f;

#pragma unroll
        for (int pass = 0; pass < 2; ++pass) {
            int lt  = pass * 32 + lr;  // local tok 0..63
            int tok = sub * 64 + lt;
            int op  = orig_pos(kb * 128 + tok);
            const float* kr = k + ((size_t)op * 8 + h) * 128;
            const float* vr = v + ((size_t)op * 8 + h) * 128;
#pragma unroll
            for (int j = 0; j < 4; ++j) {
                int d = ld4 + j * 32;
                float4v xk = *reinterpret_cast<const float4v*>(kr + d);
                float4v xv = *reinterpret_cast<const float4v*>(vr + d);
                half4 hk;
                half2v hv0, hv1;
#pragma unroll
                for (int i = 0; i < 4; ++i) { hk[i] = (_Float16)xk[i]; ksum[j * 4 + i] += xk[i]; }
                hv0[0] = (_Float16)xv[0]; hv0[1] = (_Float16)xv[1];
                hv1[0] = (_Float16)xv[2]; hv1[1] = (_Float16)xv[3];
                *reinterpret_cast<half4*>(&KsL[lt * KROW + d]) = hk;
                *reinterpret_cast<half2v*>(&VsL[lt * VSROW + d]) = hv0;
                *reinterpret_cast<half2v*>(&VsL[lt * VSROW + d + 2]) = hv1;
            }
        }
#pragma unroll
        for (int j = 0; j < 4; ++j)
#pragma unroll
            for (int i = 0; i < 4; ++i)
                Rs[lr * 128 + ld4 + j * 32 + i] = ksum[j * 4 + i];
        __syncthreads();

        { // Kc: stream LDS tile out as coalesced 16B x 256-lane chunks
            const float4v* src = reinterpret_cast<const float4v*>(KsL);
            float4v* dst = reinterpret_cast<float4v*>(Kc + ((size_t)((h * 36 + kb) * 128) + sub * 64) * KROW);
            for (int i = tid; i < 1088; i += 256) dst[i] = src[i];
        }

        { // V^T -> Vt [h][kb][sub][dim][VROW/2], dword-packed token pairs
            const unsigned short* Vsu = (const unsigned short*)VsL;
            unsigned* vo = Vt32 + (size_t)((h * 36 + kb) * 2 + sub) * 128 * (VROW / 2);
#pragma unroll
            for (int it = 0; it < 16; ++it) {
                int i   = it * 256 + tid;
                int tw  = i & 31;
                int dim = i >> 5;
                unsigned lo = Vsu[(2 * tw) * VSROW + dim];
                unsigned hi = Vsu[(2 * tw + 1) * VSROW + dim];
                vo[dim * (VROW / 2) + tw] = (hi << 16) | lo;
            }
        }

        if (tid < 128) { // pooled-K partial sum (no /128: exact 2^7 scale)
            float s = 0.f;
#pragma unroll
            for (int g = 0; g < 32; ++g) s += Rs[g * 128 + tid];
            kpart[(size_t)((h * 36 + kb) * 2 + sub) * 128 + tid] = s;
        }
    } else {  // pooled-Q sums (no /128)
        int bx2 = bx - 576;
        int kb  = bx2 % 36;
        int h   = bx2 / 36;

        int dq = (tid & 31) << 2;
        int g  = tid >> 5;
        float4v acc = {0.f, 0.f, 0.f, 0.f};
#pragma unroll
        for (int it = 0; it < 16; ++it) {
            int t  = g + it * 8;
            int op = orig_pos(kb * 128 + t);
            float4v x = *reinterpret_cast<const float4v*>(q + ((size_t)op * 8 + h) * 128 + dq);
            acc[0] += x[0]; acc[1] += x[1]; acc[2] += x[2]; acc[3] += x[3];
        }
#pragma unroll
        for (int i = 0; i < 4; ++i) Rs[g * 128 + dq + i] = acc[i];
        __syncthreads();

        if (tid < 128) {
            float s = 0.f;
#pragma unroll
            for (int g2 = 0; g2 < 8; ++g2) s += Rs[g2 * 128 + tid];
            qp[(h * 36 + kb) * 128 + tid] = s;
        }
    }
}

// ---------------- flash ----------------
// grid 864, 256 threads (4 waves), 4 wg/CU (LDS 36.3 KB). Slot-aware task map:
// c = b&255 (CU), s = b>>8 (slot), h = c&7, u = c>>3 (0..31).
//   u<12  (4-slot CUs): heavy at s=0 (j=u);            light s=1..3 (jl=u*3+s-1)
//   12<=u<28:           heavy at s=0,1 (j=12+(u-12)*2+s); light s=2 (jl=36+u-12)
//   u>=28:              heavy at s=0 (j=44+u-28);      light s=1,2 (jl=52+(u-28)*2+s-1)
// heavy j -> qbh=j>>3, half=(j>>2)&1, chunk=j&3 (9 kb = 18 tiles). pidx = h*48+j.
// wave = (rh=wave&1, th=wave>>1): rows rh*32+rg*16+.., tokens th*32+[0..31].
__global__ __launch_bounds__(256, 4) void flash_kernel(const float* __restrict__ q,
                                                       const short* __restrict__ Kc,
                                                       const short* __restrict__ Vt,
                                                       const float* __restrict__ qp,
                                                       const float* __restrict__ kpart,
                                                       float* __restrict__ out,
                                                       float* __restrict__ pO,
                                                       float* __restrict__ pL) {
    __shared__ __align__(16) short Ks[64 * KROW];      // 17408 B; P buffer aliases first 10240 B
    __shared__ __align__(16) short Vsh[128 * VROW];    // 18432 B
    __shared__ int Ls[40];
    __shared__ float Lf[64];

    int b = blockIdx.x;
    int c = b & 255, s = b >> 8;
    int h = c & 7, u = c >> 3;
    int qb, half, nkb = 0, kbase = 0, pidx = -1, qbh = 0;
    {
        bool heavy; int j, jl;
        if (u < 12)      { heavy = (s == 0); j = u;                  jl = u * 3 + (s - 1); }
        else if (u < 28) { heavy = (s <= 1); j = 12 + (u - 12) * 2 + s; jl = 36 + (u - 12); }
        else             { heavy = (s == 0); j = 44 + (u - 28);      jl = 52 + (u - 28) * 2 + (s - 1); }
        if (heavy) {
            qbh = j >> 3;
            int r = j & 7;
            half = r >> 2;
            int chunk = r & 3;
            qb = 30 + qbh; nkb = 9; kbase = chunk * 9; pidx = h * 48 + j;
        } else {
            qb = jl >> 1; half = jl & 1;
        }
    }

    int tid = threadIdx.x, wave = tid >> 6, lane = tid & 63;
    int m16 = lane & 15, quad = lane >> 4;
    int rh = wave & 1, th = wave >> 1;

    constexpr float kScale = 0.08838834764831845f * 1.4426950408889634f;

    // Q A-frags: 2 row-groups per wave (rows rh*32 + rg*16 + m16), pre-scaled
    half8 aq[2][4];
#pragma unroll
    for (int rg = 0; rg < 2; ++rg) {
        int qrow_frag = qb * 128 + half * 64 + rh * 32 + rg * 16 + m16;
        const float* qrp = q + ((size_t)orig_pos(qrow_frag) * 8 + h) * 128;
#pragma unroll
        for (int kc = 0; kc < 4; ++kc) {
            float4v x0 = *reinterpret_cast<const float4v*>(qrp + kc * 32 + quad * 8);
            float4v x1 = *reinterpret_cast<const float4v*>(qrp + kc * 32 + quad * 8 + 4);
#pragma unroll
            for (int j2 = 0; j2 < 4; ++j2) {
                aq[rg][kc][j2]     = (_Float16)(x0[j2] * kScale);
                aq[rg][kc][4 + j2] = (_Float16)(x1[j2] * kScale);
            }
        }
    }

    // fused selection (light tasks only; wave 0); kp = kpart0 + kpart1 (exact 2^7 scale vs mean)
    if (pidx < 0 && wave == 0) {
        float sc = -1e30f;
        if (lane < 36) {
            const float4v* qv  = (const float4v*)(qp + (h * 36 + qb) * 128);
            const float4v* kv0 = (const float4v*)(kpart + (size_t)((h * 36 + lane) * 2) * 128);
            const float4v* kv1 = kv0 + 32;
            float acc = 0.f;
            for (int i = 0; i < 32; ++i) {
                float4v a = qv[i], b0 = kv0[i], b1 = kv1[i];
                acc += a[0] * (b0[0] + b1[0]) + a[1] * (b0[1] + b1[1])
                     + a[2] * (b0[2] + b1[2]) + a[3] * (b0[3] + b1[3]);
            }
            sc = acc;
        }
        float tmp = sc;
        float thr = 0.f;
        for (int i = 0; i < 4; ++i) {
            float mx = tmp;
            for (int off = 1; off < 64; off <<= 1) mx = fmaxf(mx, __shfl_xor(mx, off));
            thr = mx;
            unsigned long long bal = __ballot(tmp == mx);
            int low = __ffsll(bal) - 1;
            if (lane == low) tmp = -3e38f;
        }
        bool keep = (lane < 36) && ((sc >= thr) || (lane >= 30));
        unsigned long long mk = __ballot(keep);
        if (lane == 0) Ls[0] = __popcll(mk);
        if (keep) {
            int pos = __popcll(mk & ((1ull << lane) - 1ull));
            Ls[1 + pos] = lane;
        }
    }
    __syncthreads();
    if (pidx < 0) nkb = Ls[0];

    float l_r[2][4];
    float4v o[2][8];
#pragma unroll
    for (int rg = 0; rg < 2; ++rg) {
#pragma unroll
        for (int r = 0; r < 4; ++r) l_r[rg][r] = 0.f;
#pragma unroll
        for (int dt = 0; dt < 8; ++dt) { o[rg][dt][0] = 0.f; o[rg][dt][1] = 0.f; o[rg][dt][2] = 0.f; o[rg][dt][3] = 0.f; }
    }

    short* Phw = ((short*)Ks) + wave * (32 * PPROW);   // P aliases Ks; guarded by barrier C

    int ntile = nkb * 2;
    for (int it = 0; it < ntile; ++it) {
        int kb  = (pidx >= 0) ? (kbase + (it >> 1)) : Ls[1 + (it >> 1)];
        int sub = it & 1;
        const char* gK = (const char*)(Kc + ((size_t)((h * 36 + kb) * 128) + sub * 64) * KROW);
        const char* gV = (const char*)(Vt + (size_t)((h * 36 + kb) * 2 + sub) * 128 * VROW);

        __syncthreads();   // A: previous tile's LDS reads (incl. P) complete
        {   // 35 x 1KB chunks (17 K + 18 V)
            char* lK = (char*)Ks;
            char* lV = (char*)Vsh;
            int off = lane * 16;
            for (int ch = wave; ch < 35; ch += 4) {
                if (ch < 17) cp16(gK + ch * 1024 + off, lK + ch * 1024 + off);
                else         cp16(gV + (ch - 17) * 1024 + off, lV + (ch - 17) * 1024 + off);
            }
        }
        __syncthreads();   // B: staged data resident

        // S = Q K^T (this wave's 32 tokens; bk shared across 2 row-groups)
        float4v sacc[2][2];
#pragma unroll
        for (int rg = 0; rg < 2; ++rg)
#pragma unroll
            for (int nt = 0; nt < 2; ++nt) { sacc[rg][nt][0] = 0.f; sacc[rg][nt][1] = 0.f; sacc[rg][nt][2] = 0.f; sacc[rg][nt][3] = 0.f; }
#pragma unroll
        for (int nt = 0; nt < 2; ++nt)
#pragma unroll
            for (int kc = 0; kc < 4; ++kc) {
                half8 bk = *reinterpret_cast<const half8*>(&Ks[(th * 32 + nt * 16 + m16) * KROW + kc * 32 + quad * 8]);
                sacc[0][nt] = __builtin_amdgcn_mfma_f32_16x16x32_f16(aq[0][kc], bk, sacc[0][nt], 0, 0, 0);
                sacc[1][nt] = __builtin_amdgcn_mfma_f32_16x16x32_f16(aq[1][kc], bk, sacc[1][nt], 0, 0, 0);
            }

        // fixed-m softmax: p = 2^s (scale pre-folded into Q); lane-local l accum
#pragma unroll
        for (int rg = 0; rg < 2; ++rg)
#pragma unroll
            for (int r = 0; r < 4; ++r) {
                float p0 = exp2f(sacc[rg][0][r]);
                float p1 = exp2f(sacc[rg][1][r]);
                sacc[rg][0][r] = p0; sacc[rg][1][r] = p1;
                l_r[rg][r] += p0 + p1;
            }

        __syncthreads();   // C: all waves' K reads done; safe to write P into Ks region

        // P -> fp16 LDS (wave-private region inside Ks)
#pragma unroll
        for (int rg = 0; rg < 2; ++rg)
#pragma unroll
            for (int nt = 0; nt < 2; ++nt)
#pragma unroll
                for (int r = 0; r < 4; ++r) {
                    union { _Float16 hf; short sv; } cv;
                    cv.hf = (_Float16)sacc[rg][nt][r];
                    Phw[(rg * 16 + quad * 4 + r) * PPROW + nt * 16 + m16] = cv.sv;
                }
        half8 ap[2];
#pragma unroll
        for (int rg = 0; rg < 2; ++rg)
            ap[rg] = *reinterpret_cast<const half8*>(&Phw[(rg * 16 + m16) * PPROW + quad * 8]);

        // O += P V over this wave's 32 tokens (bv shared across 2 row-groups)
#pragma unroll
        for (int dt = 0; dt < 8; ++dt) {
            half8 bv = *reinterpret_cast<const half8*>(&Vsh[(dt * 16 + m16) * VROW + th * 32 + quad * 8]);
            o[0][dt] = __builtin_amdgcn_mfma_f32_16x16x32_f16(ap[0], bv, o[0][dt], 0, 0, 0);
            o[1][dt] = __builtin_amdgcn_mfma_f32_16x16x32_f16(ap[1], bv, o[1][dt], 0, 0, 0);
        }
    }

    // reduce l across the 16 cols held per lane-group
#pragma unroll
    for (int rg = 0; rg < 2; ++rg)
#pragma unroll
        for (int r = 0; r < 4; ++r)
            for (int sh = 1; sh < 16; sh <<= 1) l_r[rg][r] += __shfl_xor(l_r[rg][r], sh);

    // cross-wave reduction over token halves (th=1 -> LDS, th=0 adds + writes out)
    __syncthreads();   // all waves done with Ks/Vsh (incl. P reads)
    {
        float* red = rh ? (float*)Vsh : (float*)Ks;   // 32 rows x stride 132 floats = 16896B
        if (th == 1) {
#pragma unroll
            for (int rg = 0; rg < 2; ++rg) {
#pragma unroll
                for (int dt = 0; dt < 8; ++dt)
#pragma unroll
                    for (int r = 0; r < 4; ++r)
                        red[(rg * 16 + quad * 4 + r) * 132 + dt * 16 + m16] = o[rg][dt][r];
                if (m16 == 0)
#pragma unroll
                    for (int r = 0; r < 4; ++r)
                        Lf[rh * 32 + rg * 16 + quad * 4 + r] = l_r[rg][r];
            }
        }
        __syncthreads();
        if (th == 0) {
#pragma unroll
            for (int rg = 0; rg < 2; ++rg)
#pragma unroll
                for (int dt = 0; dt < 8; ++dt)
#pragma unroll
                    for (int r = 0; r < 4; ++r)
                        o[rg][dt][r] += red[(rg * 16 + quad * 4 + r) * 132 + dt * 16 + m16];

            if (pidx >= 0) {
                float* po = pO + (size_t)pidx * 8192;
#pragma unroll
                for (int rg = 0; rg < 2; ++rg)
#pragma unroll
                    for (int r = 0; r < 4; ++r) {
                        int row = rh * 32 + rg * 16 + quad * 4 + r;
                        float lt2 = l_r[rg][r] + Lf[row];
#pragma unroll
                        for (int dt = 0; dt < 8; ++dt)
                            po[row * 128 + dt * 16 + m16] = o[rg][dt][r];
                        if (m16 == 0) pL[pidx * 64 + row] = lt2;
                    }
            } else {
#pragma unroll
                for (int rg = 0; rg < 2; ++rg)
#pragma unroll
                    for (int r = 0; r < 4; ++r) {
                        int row = rh * 32 + rg * 16 + quad * 4 + r;
                        int qrow = qb * 128 + half * 64 + row;
                        size_t base = ((size_t)orig_pos(qrow) * 8 + h) * 128;
                        float inv = 1.f / (l_r[rg][r] + Lf[row]);
#pragma unroll
                        for (int dt = 0; dt < 8; ++dt)
                            out[base + dt * 16 + m16] = o[rg][dt][r] * inv;
                    }
            }
        }
    }
}

// ---------------- combine (heavy only; fixed-m partials sum linearly; 4 chunks) ----------------
__global__ void combine_kernel(const float* __restrict__ pO, const float* __restrict__ pL,
                               float* __restrict__ out) {
    int gb = blockIdx.x;             // 768
    int gid = gb >> 3;               // 96 = (h,qbh,half)
    int rg  = gb & 7;                // row-group: 8 rows each
    int h    = gid / 12;
    int rem  = gid % 12;
    int qbh  = rem >> 1;
    int half = rem & 1;
    int qb   = 30 + qbh;
    int p0   = h * 48 + qbh * 8 + half * 4;   // partials p0+0..3

    int tid = threadIdx.x;
    int d   = tid & 127;
    int r0  = tid >> 7;
#pragma unroll
    for (int itr = 0; itr < 4; ++itr) {
        int row = rg * 8 + r0 + itr * 2;
        float l = pL[(p0 + 0) * 64 + row] + pL[(p0 + 1) * 64 + row]
                + pL[(p0 + 2) * 64 + row] + pL[(p0 + 3) * 64 + row];
        float acc = pO[(size_t)(p0 + 0) * 8192 + row * 128 + d]
                  + pO[(size_t)(p0 + 1) * 8192 + row * 128 + d]
                  + pO[(size_t)(p0 + 2) * 8192 + row * 128 + d]
                  + pO[(size_t)(p0 + 3) * 8192 + row * 128 + d];
        int qrow = qb * 128 + half * 64 + row;
        out[((size_t)orig_pos(qrow) * 8 + h) * 128 + d] = acc / l;
    }
}

extern "C" void kernel_launch(void* const* d_in, const int* in_sizes, int n_in,
                              void* d_out, int out_size, void* d_ws, size_t ws_size,
                              hipStream_t stream) {
    const float* q = (const float*)d_in[0];
    const float* k = (const float*)d_in[1];
    const float* v = (const float*)d_in[2];
    float* out = (float*)d_out;

    char* w = (char*)d_ws;
    short* Kc    = (short*)(w);                 // 10,027,008 B
    short* Vt    = (short*)(w + 10027008);      // 10,616,832 B (VROW=72)
    float* qp    = (float*)(w + 20643840);      // 147,456 B
    float* kpart = (float*)(w + 20791296);      // 294,912 B
    float* pL    = (float*)(w + 21086208);      // 98,304 B   (384 x 64)
    float* pO    = (float*)(w + 21184512);      // 12,582,912 B (384 x 8192) -> total ~33.8 MB

    prep_kernel<<<dim3(864), dim3(256), 0, stream>>>(q, k, v, Kc, (unsigned*)Vt, qp, kpart);
    flash_kernel<<<dim3(864), dim3(256), 0, stream>>>(q, Kc, Vt, qp, kpart, out, pO, pL);
    combine_kernel<<<dim3(768), dim3(256), 0, stream>>>(pO, pL, out);
}

// Round 8
// 198.930 us; speedup vs baseline: 1.3553x; 1.3553x over previous
//
#include <hip/hip_runtime.h>

// Rainfusion blockwise sparse attention. f32 in/out; fp16 MFMA inside.
// Fixed-m softmax (m=0). R8: R7 minus the spill — launch_bounds(256,3) (R7's
// (256,4) forced VGPR 64 -> accumulator spill -> 280MB scratch traffic).
// Keeps: P aliased into Ks (LDS 36.3KB -> 4 wg/CU by LDS), heavy 4-chunk split
// (18 tiles ~ light load), merged prep (1 node), 4-partial combine.
// Task map reverted to natural order (b<384 heavy, h=b&7 XCD affinity).

typedef __attribute__((ext_vector_type(8))) _Float16 half8;
typedef __attribute__((ext_vector_type(4))) _Float16 half4;
typedef __attribute__((ext_vector_type(2))) _Float16 half2v;
typedef __attribute__((ext_vector_type(4))) float float4v;

#define KROW 136   // shorts per K row: 128 dims + 8 pad
#define VROW 72    // shorts per V^T row: 64 toks + 8 pad (144B rows, 16B-aligned)
#define VSROW 138  // prep-local V staging stride (conflict-free transpose reads)
#define PPROW 40   // shorts per P row: 32 toks + 8 pad (80B rows, 16B-aligned)

__device__ __forceinline__ int orig_pos(int j) {
    if (j >= 3840) return (j < 4224) ? (j - 3840) : j;
    int blk = j >> 7;
    int r   = j & 127;
    int f   = blk / 6;
    int rem = blk - f * 6;
    int b2  = rem / 3;
    int e   = rem - b2 * 3;
    int a   = r >> 6;
    int c   = (r >> 3) & 7;
    int g   = r & 7;
    return 384 + (f * 2 + a) * 384 + (b2 * 8 + c) * 24 + e * 8 + g;
}

__device__ __forceinline__ void cp16(const void* g, void* l) {
    __builtin_amdgcn_global_load_lds((const __attribute__((address_space(1))) void*)g,
                                     (__attribute__((address_space(3))) void*)l, 16, 0, 0);
}

// ---------------- prep: grid 864. bx<576: conv+transpose+pooled-K. bx>=576: pooled-Q. ----------------
__global__ __launch_bounds__(256) void prep_kernel(const float* __restrict__ q,
                                                   const float* __restrict__ k,
                                                   const float* __restrict__ v,
                                                   short* __restrict__ Kc,
                                                   unsigned* __restrict__ Vt32,
                                                   float* __restrict__ qp,
                                                   float* __restrict__ kpart) {
    __shared__ __align__(16) short KsL[64 * KROW];   // 17408 B (mirrors global Kc layout)
    __shared__ short VsL[64 * VSROW];                // 17664 B
    __shared__ float Rs[32 * 128];                   // 16384 B
    int bx  = blockIdx.x;
    int tid = threadIdx.x;

    if (bx < 576) {  // conv: K/V fp16 tiles + pooled-K partials
        int sub = bx & 1;
        int kb  = (bx >> 1) % 36;
        int h   = bx / 72;

        int lr  = tid >> 3;            // row group 0..31
        int ld4 = (tid & 7) << 2;      // float offset 0,4,..,28

        float ksum[16];
#pragma unroll
        for (int i = 0; i < 16; ++i) ksum[i] = 0.f;

#pragma unroll
        for (int pass = 0; pass < 2; ++pass) {
            int lt  = pass * 32 + lr;  // local tok 0..63
            int tok = sub * 64 + lt;
            int op  = orig_pos(kb * 128 + tok);
            const float* kr = k + ((size_t)op * 8 + h) * 128;
            const float* vr = v + ((size_t)op * 8 + h) * 128;
#pragma unroll
            for (int j = 0; j < 4; ++j) {
                int d = ld4 + j * 32;
                float4v xk = *reinterpret_cast<const float4v*>(kr + d);
                float4v xv = *reinterpret_cast<const float4v*>(vr + d);
                half4 hk;
                half2v hv0, hv1;
#pragma unroll
                for (int i = 0; i < 4; ++i) { hk[i] = (_Float16)xk[i]; ksum[j * 4 + i] += xk[i]; }
                hv0[0] = (_Float16)xv[0]; hv0[1] = (_Float16)xv[1];
                hv1[0] = (_Float16)xv[2]; hv1[1] = (_Float16)xv[3];
                *reinterpret_cast<half4*>(&KsL[lt * KROW + d]) = hk;
                *reinterpret_cast<half2v*>(&VsL[lt * VSROW + d]) = hv0;
                *reinterpret_cast<half2v*>(&VsL[lt * VSROW + d + 2]) = hv1;
            }
        }
#pragma unroll
        for (int j = 0; j < 4; ++j)
#pragma unroll
            for (int i = 0; i < 4; ++i)
                Rs[lr * 128 + ld4 + j * 32 + i] = ksum[j * 4 + i];
        __syncthreads();

        { // Kc: stream LDS tile out as coalesced 16B x 256-lane chunks
            const float4v* src = reinterpret_cast<const float4v*>(KsL);
            float4v* dst = reinterpret_cast<float4v*>(Kc + ((size_t)((h * 36 + kb) * 128) + sub * 64) * KROW);
            for (int i = tid; i < 1088; i += 256) dst[i] = src[i];
        }

        { // V^T -> Vt [h][kb][sub][dim][VROW/2], dword-packed token pairs
            const unsigned short* Vsu = (const unsigned short*)VsL;
            unsigned* vo = Vt32 + (size_t)((h * 36 + kb) * 2 + sub) * 128 * (VROW / 2);
#pragma unroll
            for (int it = 0; it < 16; ++it) {
                int i   = it * 256 + tid;
                int tw  = i & 31;
                int dim = i >> 5;
                unsigned lo = Vsu[(2 * tw) * VSROW + dim];
                unsigned hi = Vsu[(2 * tw + 1) * VSROW + dim];
                vo[dim * (VROW / 2) + tw] = (hi << 16) | lo;
            }
        }

        if (tid < 128) { // pooled-K partial sum (no /128: exact 2^7 scale)
            float s = 0.f;
#pragma unroll
            for (int g = 0; g < 32; ++g) s += Rs[g * 128 + tid];
            kpart[(size_t)((h * 36 + kb) * 2 + sub) * 128 + tid] = s;
        }
    } else {  // pooled-Q sums (no /128)
        int bx2 = bx - 576;
        int kb  = bx2 % 36;
        int h   = bx2 / 36;

        int dq = (tid & 31) << 2;
        int g  = tid >> 5;
        float4v acc = {0.f, 0.f, 0.f, 0.f};
#pragma unroll
        for (int it = 0; it < 16; ++it) {
            int t  = g + it * 8;
            int op = orig_pos(kb * 128 + t);
            float4v x = *reinterpret_cast<const float4v*>(q + ((size_t)op * 8 + h) * 128 + dq);
            acc[0] += x[0]; acc[1] += x[1]; acc[2] += x[2]; acc[3] += x[3];
        }
#pragma unroll
        for (int i = 0; i < 4; ++i) Rs[g * 128 + dq + i] = acc[i];
        __syncthreads();

        if (tid < 128) {
            float s = 0.f;
#pragma unroll
            for (int g2 = 0; g2 < 8; ++g2) s += Rs[g2 * 128 + tid];
            qp[(h * 36 + kb) * 128 + tid] = s;
        }
    }
}

// ---------------- flash ----------------
// grid 864, 256 threads (4 waves). b<384: heavy — h=b&7, j=b>>3 (0..47):
// qbh=j>>3, half=(j>>2)&1, chunk=j&3, nkb=9 (18 tiles), pidx=h*48+j.
// b>=384: light — t2=b-384, h=t2&7, rest=t2>>3: qb=rest>>1, half=rest&1.
// LDS 36.3KB -> up to 4 wg/CU (LDS-bound); VGPR free to ~170 (no spill).
// wave = (rh=wave&1, th=wave>>1): rows rh*32+rg*16+.., tokens th*32+[0..31].
__global__ __launch_bounds__(256, 3) void flash_kernel(const float* __restrict__ q,
                                                       const short* __restrict__ Kc,
                                                       const short* __restrict__ Vt,
                                                       const float* __restrict__ qp,
                                                       const float* __restrict__ kpart,
                                                       float* __restrict__ out,
                                                       float* __restrict__ pO,
                                                       float* __restrict__ pL) {
    __shared__ __align__(16) short Ks[64 * KROW];      // 17408 B; P buffer aliases first 10240 B
    __shared__ __align__(16) short Vsh[128 * VROW];    // 18432 B
    __shared__ int Ls[40];
    __shared__ float Lf[64];

    int b = blockIdx.x;
    int h, qb, half, nkb = 0, kbase = 0, pidx = -1, qbh = 0;
    if (b < 384) {
        h = b & 7;
        int j = b >> 3;                // 0..47 = qbh*8 + half*4 + chunk
        qbh = j >> 3;
        half = (j >> 2) & 1;
        int chunk = j & 3;
        qb = 30 + qbh; nkb = 9; kbase = chunk * 9; pidx = h * 48 + j;
    } else {
        int t2 = b - 384;
        h = t2 & 7;
        int rest = t2 >> 3;            // 0..59 = qb*2 + half
        qb = rest >> 1; half = rest & 1;
    }

    int tid = threadIdx.x, wave = tid >> 6, lane = tid & 63;
    int m16 = lane & 15, quad = lane >> 4;
    int rh = wave & 1, th = wave >> 1;

    constexpr float kScale = 0.08838834764831845f * 1.4426950408889634f;

    // Q A-frags: 2 row-groups per wave (rows rh*32 + rg*16 + m16), pre-scaled
    half8 aq[2][4];
#pragma unroll
    for (int rg = 0; rg < 2; ++rg) {
        int qrow_frag = qb * 128 + half * 64 + rh * 32 + rg * 16 + m16;
        const float* qrp = q + ((size_t)orig_pos(qrow_frag) * 8 + h) * 128;
#pragma unroll
        for (int kc = 0; kc < 4; ++kc) {
            float4v x0 = *reinterpret_cast<const float4v*>(qrp + kc * 32 + quad * 8);
            float4v x1 = *reinterpret_cast<const float4v*>(qrp + kc * 32 + quad * 8 + 4);
#pragma unroll
            for (int j2 = 0; j2 < 4; ++j2) {
                aq[rg][kc][j2]     = (_Float16)(x0[j2] * kScale);
                aq[rg][kc][4 + j2] = (_Float16)(x1[j2] * kScale);
            }
        }
    }

    // fused selection (light tasks only; wave 0); kp = kpart0 + kpart1 (exact 2^7 scale vs mean)
    if (pidx < 0 && wave == 0) {
        float sc = -1e30f;
        if (lane < 36) {
            const float4v* qv  = (const float4v*)(qp + (h * 36 + qb) * 128);
            const float4v* kv0 = (const float4v*)(kpart + (size_t)((h * 36 + lane) * 2) * 128);
            const float4v* kv1 = kv0 + 32;
            float acc = 0.f;
            for (int i = 0; i < 32; ++i) {
                float4v a = qv[i], b0 = kv0[i], b1 = kv1[i];
                acc += a[0] * (b0[0] + b1[0]) + a[1] * (b0[1] + b1[1])
                     + a[2] * (b0[2] + b1[2]) + a[3] * (b0[3] + b1[3]);
            }
            sc = acc;
        }
        float tmp = sc;
        float thr = 0.f;
        for (int i = 0; i < 4; ++i) {
            float mx = tmp;
            for (int off = 1; off < 64; off <<= 1) mx = fmaxf(mx, __shfl_xor(mx, off));
            thr = mx;
            unsigned long long bal = __ballot(tmp == mx);
            int low = __ffsll(bal) - 1;
            if (lane == low) tmp = -3e38f;
        }
        bool keep = (lane < 36) && ((sc >= thr) || (lane >= 30));
        unsigned long long mk = __ballot(keep);
        if (lane == 0) Ls[0] = __popcll(mk);
        if (keep) {
            int pos = __popcll(mk & ((1ull << lane) - 1ull));
            Ls[1 + pos] = lane;
        }
    }
    __syncthreads();
    if (pidx < 0) nkb = Ls[0];

    float l_r[2][4];
    float4v o[2][8];
#pragma unroll
    for (int rg = 0; rg < 2; ++rg) {
#pragma unroll
        for (int r = 0; r < 4; ++r) l_r[rg][r] = 0.f;
#pragma unroll
        for (int dt = 0; dt < 8; ++dt) { o[rg][dt][0] = 0.f; o[rg][dt][1] = 0.f; o[rg][dt][2] = 0.f; o[rg][dt][3] = 0.f; }
    }

    short* Phw = ((short*)Ks) + wave * (32 * PPROW);   // P aliases Ks; guarded by barrier C

    int ntile = nkb * 2;
    for (int it = 0; it < ntile; ++it) {
        int kb  = (pidx >= 0) ? (kbase + (it >> 1)) : Ls[1 + (it >> 1)];
        int sub = it & 1;
        const char* gK = (const char*)(Kc + ((size_t)((h * 36 + kb) * 128) + sub * 64) * KROW);
        const char* gV = (const char*)(Vt + (size_t)((h * 36 + kb) * 2 + sub) * 128 * VROW);

        __syncthreads();   // A: previous tile's LDS reads (incl. P) complete
        {   // 35 x 1KB chunks (17 K + 18 V)
            char* lK = (char*)Ks;
            char* lV = (char*)Vsh;
            int off = lane * 16;
            for (int ch = wave; ch < 35; ch += 4) {
                if (ch < 17) cp16(gK + ch * 1024 + off, lK + ch * 1024 + off);
                else         cp16(gV + (ch - 17) * 1024 + off, lV + (ch - 17) * 1024 + off);
            }
        }
        __syncthreads();   // B: staged data resident

        // S = Q K^T (this wave's 32 tokens; bk shared across 2 row-groups)
        float4v sacc[2][2];
#pragma unroll
        for (int rg = 0; rg < 2; ++rg)
#pragma unroll
            for (int nt = 0; nt < 2; ++nt) { sacc[rg][nt][0] = 0.f; sacc[rg][nt][1] = 0.f; sacc[rg][nt][2] = 0.f; sacc[rg][nt][3] = 0.f; }
#pragma unroll
        for (int nt = 0; nt < 2; ++nt)
#pragma unroll
            for (int kc = 0; kc < 4; ++kc) {
                half8 bk = *reinterpret_cast<const half8*>(&Ks[(th * 32 + nt * 16 + m16) * KROW + kc * 32 + quad * 8]);
                sacc[0][nt] = __builtin_amdgcn_mfma_f32_16x16x32_f16(aq[0][kc], bk, sacc[0][nt], 0, 0, 0);
                sacc[1][nt] = __builtin_amdgcn_mfma_f32_16x16x32_f16(aq[1][kc], bk, sacc[1][nt], 0, 0, 0);
            }

        // fixed-m softmax: p = 2^s (scale pre-folded into Q); lane-local l accum
#pragma unroll
        for (int rg = 0; rg < 2; ++rg)
#pragma unroll
            for (int r = 0; r < 4; ++r) {
                float p0 = exp2f(sacc[rg][0][r]);
                float p1 = exp2f(sacc[rg][1][r]);
                sacc[rg][0][r] = p0; sacc[rg][1][r] = p1;
                l_r[rg][r] += p0 + p1;
            }

        __syncthreads();   // C: all waves' K reads done; safe to write P into Ks region

        // P -> fp16 LDS (wave-private region inside Ks)
#pragma unroll
        for (int rg = 0; rg < 2; ++rg)
#pragma unroll
            for (int nt = 0; nt < 2; ++nt)
#pragma unroll
                for (int r = 0; r < 4; ++r) {
                    union { _Float16 hf; short sv; } cv;
                    cv.hf = (_Float16)sacc[rg][nt][r];
                    Phw[(rg * 16 + quad * 4 + r) * PPROW + nt * 16 + m16] = cv.sv;
                }
        half8 ap[2];
#pragma unroll
        for (int rg = 0; rg < 2; ++rg)
            ap[rg] = *reinterpret_cast<const half8*>(&Phw[(rg * 16 + m16) * PPROW + quad * 8]);

        // O += P V over this wave's 32 tokens (bv shared across 2 row-groups)
#pragma unroll
        for (int dt = 0; dt < 8; ++dt) {
            half8 bv = *reinterpret_cast<const half8*>(&Vsh[(dt * 16 + m16) * VROW + th * 32 + quad * 8]);
            o[0][dt] = __builtin_amdgcn_mfma_f32_16x16x32_f16(ap[0], bv, o[0][dt], 0, 0, 0);
            o[1][dt] = __builtin_amdgcn_mfma_f32_16x16x32_f16(ap[1], bv, o[1][dt], 0, 0, 0);
        }
    }

    // reduce l across the 16 cols held per lane-group
#pragma unroll
    for (int rg = 0; rg < 2; ++rg)
#pragma unroll
        for (int r = 0; r < 4; ++r)
            for (int sh = 1; sh < 16; sh <<= 1) l_r[rg][r] += __shfl_xor(l_r[rg][r], sh);

    // cross-wave reduction over token halves (th=1 -> LDS, th=0 adds + writes out)
    __syncthreads();   // all waves done with Ks/Vsh (incl. P reads)
    {
        float* red = rh ? (float*)Vsh : (float*)Ks;   // 32 rows x stride 132 floats = 16896B
        if (th == 1) {
#pragma unroll
            for (int rg = 0; rg < 2; ++rg) {
#pragma unroll
                for (int dt = 0; dt < 8; ++dt)
#pragma unroll
                    for (int r = 0; r < 4; ++r)
                        red[(rg * 16 + quad * 4 + r) * 132 + dt * 16 + m16] = o[rg][dt][r];
                if (m16 == 0)
#pragma unroll
                    for (int r = 0; r < 4; ++r)
                        Lf[rh * 32 + rg * 16 + quad * 4 + r] = l_r[rg][r];
            }
        }
        __syncthreads();
        if (th == 0) {
#pragma unroll
            for (int rg = 0; rg < 2; ++rg)
#pragma unroll
                for (int dt = 0; dt < 8; ++dt)
#pragma unroll
                    for (int r = 0; r < 4; ++r)
                        o[rg][dt][r] += red[(rg * 16 + quad * 4 + r) * 132 + dt * 16 + m16];

            if (pidx >= 0) {
                float* po = pO + (size_t)pidx * 8192;
#pragma unroll
                for (int rg = 0; rg < 2; ++rg)
#pragma unroll
                    for (int r = 0; r < 4; ++r) {
                        int row = rh * 32 + rg * 16 + quad * 4 + r;
                        float lt2 = l_r[rg][r] + Lf[row];
#pragma unroll
                        for (int dt = 0; dt < 8; ++dt)
                            po[row * 128 + dt * 16 + m16] = o[rg][dt][r];
                        if (m16 == 0) pL[pidx * 64 + row] = lt2;
                    }
            } else {
#pragma unroll
                for (int rg = 0; rg < 2; ++rg)
#pragma unroll
                    for (int r = 0; r < 4; ++r) {
                        int row = rh * 32 + rg * 16 + quad * 4 + r;
                        int qrow = qb * 128 + half * 64 + row;
                        size_t base = ((size_t)orig_pos(qrow) * 8 + h) * 128;
                        float inv = 1.f / (l_r[rg][r] + Lf[row]);
#pragma unroll
                        for (int dt = 0; dt < 8; ++dt)
                            out[base + dt * 16 + m16] = o[rg][dt][r] * inv;
                    }
            }
        }
    }
}

// ---------------- combine (heavy only; fixed-m partials sum linearly; 4 chunks) ----------------
__global__ void combine_kernel(const float* __restrict__ pO, const float* __restrict__ pL,
                               float* __restrict__ out) {
    int gb = blockIdx.x;             // 768
    int gid = gb >> 3;               // 96 = (h,qbh,half)
    int rg  = gb & 7;                // row-group: 8 rows each
    int h    = gid / 12;
    int rem  = gid % 12;
    int qbh  = rem >> 1;
    int half = rem & 1;
    int qb   = 30 + qbh;
    int p0   = h * 48 + qbh * 8 + half * 4;   // partials p0+0..3

    int tid = threadIdx.x;
    int d   = tid & 127;
    int r0  = tid >> 7;
#pragma unroll
    for (int itr = 0; itr < 4; ++itr) {
        int row = rg * 8 + r0 + itr * 2;
        float l = pL[(p0 + 0) * 64 + row] + pL[(p0 + 1) * 64 + row]
                + pL[(p0 + 2) * 64 + row] + pL[(p0 + 3) * 64 + row];
        float acc = pO[(size_t)(p0 + 0) * 8192 + row * 128 + d]
                  + pO[(size_t)(p0 + 1) * 8192 + row * 128 + d]
                  + pO[(size_t)(p0 + 2) * 8192 + row * 128 + d]
                  + pO[(size_t)(p0 + 3) * 8192 + row * 128 + d];
        int qrow = qb * 128 + half * 64 + row;
        out[((size_t)orig_pos(qrow) * 8 + h) * 128 + d] = acc / l;
    }
}

extern "C" void kernel_launch(void* const* d_in, const int* in_sizes, int n_in,
                              void* d_out, int out_size, void* d_ws, size_t ws_size,
                              hipStream_t stream) {
    const float* q = (const float*)d_in[0];
    const float* k = (const float*)d_in[1];
    const float* v = (const float*)d_in[2];
    float* out = (float*)d_out;

    char* w = (char*)d_ws;
    short* Kc    = (short*)(w);                 // 10,027,008 B
    short* Vt    = (short*)(w + 10027008);      // 10,616,832 B (VROW=72)
    float* qp    = (float*)(w + 20643840);      // 147,456 B
    float* kpart = (float*)(w + 20791296);      // 294,912 B
    float* pL    = (float*)(w + 21086208);      // 98,304 B   (384 x 64)
    float* pO    = (float*)(w + 21184512);      // 12,582,912 B (384 x 8192) -> total ~33.8 MB

    prep_kernel<<<dim3(864), dim3(256), 0, stream>>>(q, k, v, Kc, (unsigned*)Vt, qp, kpart);
    flash_kernel<<<dim3(864), dim3(256), 0, stream>>>(q, Kc, Vt, qp, kpart, out, pO, pL);
    combine_kernel<<<dim3(768), dim3(256), 0, stream>>>(pO, pL, out);
}

// Round 9
// 168.287 us; speedup vs baseline: 1.6021x; 1.1821x over previous
//
#include <hip/hip_runtime.h>

// Rainfusion blockwise sparse attention. f32 in/out; fp16 MFMA inside.
// Fixed-m softmax (m=0). FINAL (R9) = verbatim revert to R4, the session's best
// (169.7us total, flash 75.4us): token-split waves — 4 waves/wg, each wave =
// (rowhalf, tokhalf) 32 rows x 32 toks; K/V B-frags read once per wave, reused
// across 2 row-groups; 3 wg/CU co-residency (grid 768); cross-wave O/l reduction
// through dead Ks/Vsh; Q pre-scaled at fp16 cvt; separate Ph buffer (no P-alias
// barrier); prep split conv|pooled (1152); combine regridded (768).
// Probed and rejected: intra-wg pipelining (R1), 2-wave wgs (R2), fence-folded
// combine (R6), launch_bounds(256,4) [VGPR-64 spill, R7], P-alias+4-chunk (R8).

typedef __attribute__((ext_vector_type(8))) _Float16 half8;
typedef __attribute__((ext_vector_type(4))) _Float16 half4;
typedef __attribute__((ext_vector_type(4))) float float4v;

#define KROW 136   // shorts per K row: 128 dims + 8 pad
#define VROW 72    // shorts per V^T row: 64 toks + 8 pad (144B rows, 16B-aligned)
#define PPROW 40   // shorts per P row: 32 toks + 8 pad (80B rows, 16B-aligned)

__device__ __forceinline__ int orig_pos(int j) {
    if (j >= 3840) return (j < 4224) ? (j - 3840) : j;
    int blk = j >> 7;
    int r   = j & 127;
    int f   = blk / 6;
    int rem = blk - f * 6;
    int b2  = rem / 3;
    int e   = rem - b2 * 3;
    int a   = r >> 6;
    int c   = (r >> 3) & 7;
    int g   = r & 7;
    return 384 + (f * 2 + a) * 384 + (b2 * 8 + c) * 24 + e * 8 + g;
}

__device__ __forceinline__ void cp16(const void* g, void* l) {
    __builtin_amdgcn_global_load_lds((const __attribute__((address_space(1))) void*)g,
                                     (__attribute__((address_space(3))) void*)l, 16, 0, 0);
}

// ---------------- prep: grid 1152. bx<576: conv+transpose. bx>=576: pooled mean. ----------------
__global__ __launch_bounds__(256) void prep_kernel(const float* __restrict__ q,
                                                   const float* __restrict__ k,
                                                   const float* __restrict__ v,
                                                   short* __restrict__ Kc,
                                                   unsigned* __restrict__ Vt32,
                                                   float* __restrict__ qp,
                                                   float* __restrict__ kp) {
    __shared__ short Vs[64 * KROW];
    __shared__ float Rs[8 * 128];
    int bx  = blockIdx.x;
    int tid = threadIdx.x;

    if (bx < 576) {  // conv: 64 toks -> Kc fp16 + Vs (LDS); then V^T transpose -> Vt
        int sub = bx & 1;
        int kb  = (bx >> 1) % 36;
        int h   = bx / 72;

        int lr = tid >> 3;             // row group 0..31
        int ld = (tid & 7) << 2;       // float offset 0..28
#pragma unroll
        for (int pass = 0; pass < 2; ++pass) {
            int lt  = pass * 32 + lr;  // local tok 0..63
            int tok = sub * 64 + lt;
            int op  = orig_pos(kb * 128 + tok);
            const float* kr = k + ((size_t)op * 8 + h) * 128;
            const float* vr = v + ((size_t)op * 8 + h) * 128;
            short* ko = Kc + ((size_t)(h * 36 + kb) * 128 + tok) * KROW;
#pragma unroll
            for (int j = 0; j < 4; ++j) {
                int d = ld + j * 32;
                float4v xk = *reinterpret_cast<const float4v*>(kr + d);
                float4v xv = *reinterpret_cast<const float4v*>(vr + d);
                half4 hk, hv;
#pragma unroll
                for (int i = 0; i < 4; ++i) { hk[i] = (_Float16)xk[i]; hv[i] = (_Float16)xv[i]; }
                *reinterpret_cast<half4*>(ko + d) = hk;
                *reinterpret_cast<half4*>(&Vs[lt * KROW + d]) = hv;
            }
        }
        __syncthreads();

        { // V^T -> Vt [h][kb][sub][dim][VROW/2], dword-packed token pairs
            const unsigned short* Vsu = (const unsigned short*)Vs;
            unsigned* vo = Vt32 + (size_t)((h * 36 + kb) * 2 + sub) * 128 * (VROW / 2);
#pragma unroll
            for (int it = 0; it < 16; ++it) {
                int i   = it * 256 + tid;
                int tw  = i & 31;
                int dim = i >> 5;
                unsigned lo = Vsu[(2 * tw) * KROW + dim];
                unsigned hi = Vsu[(2 * tw + 1) * KROW + dim];
                vo[dim * (VROW / 2) + tw] = (hi << 16) | lo;
            }
        }
    } else {  // pooled mean over the full 128-token block: sub=0 -> K, sub=1 -> Q
        int bx2 = bx - 576;
        int sub = bx2 & 1;
        int kb  = (bx2 >> 1) % 36;
        int h   = bx2 / 72;

        const float* arr = sub ? q : k;
        int dq = (tid & 31) << 2;
        int g  = tid >> 5;
        float4v acc = {0.f, 0.f, 0.f, 0.f};
#pragma unroll
        for (int it = 0; it < 16; ++it) {
            int t  = g + it * 8;
            int op = orig_pos(kb * 128 + t);
            float4v x = *reinterpret_cast<const float4v*>(arr + ((size_t)op * 8 + h) * 128 + dq);
            acc[0] += x[0]; acc[1] += x[1]; acc[2] += x[2]; acc[3] += x[3];
        }
#pragma unroll
        for (int i = 0; i < 4; ++i) Rs[g * 128 + dq + i] = acc[i];
        __syncthreads();

        if (tid < 128) {
            float s = 0.f;
#pragma unroll
            for (int g2 = 0; g2 < 8; ++g2) s += Rs[g2 * 128 + tid];
            float* outp = sub ? qp : kp;
            outp[(h * 36 + kb) * 128 + tid] = s * (1.f / 128.f);
        }
    }
}

// ---------------- flash ----------------
// grid 768, 256 threads (4 waves). wave = (rh = wave&1, th = wave>>1):
// rows rh*32 + rg*16 + quad*4 + r, tokens th*32 + [0..31]. 3 wg/CU = 12 waves/CU.
// h = blockIdx%8 (XCD affinity). 0..287 heavy, 288..767 light (self-select, wave 0).
__global__ __launch_bounds__(256, 3) void flash_kernel(const float* __restrict__ q,
                                                       const short* __restrict__ Kc,
                                                       const short* __restrict__ Vt,
                                                       const float* __restrict__ qp,
                                                       const float* __restrict__ kp,
                                                       float* __restrict__ out,
                                                       float* __restrict__ pO,
                                                       float* __restrict__ pL) {
    __shared__ __align__(16) short Ks[64 * KROW];      // 17408 B (also f32 O-red rh=0: 16896B)
    __shared__ __align__(16) short Vsh[128 * VROW];    // 18432 B (also f32 O-red rh=1)
    __shared__ __align__(16) short Ph[4 * 32 * PPROW]; // 10240 B
    __shared__ int Ls[40];
    __shared__ float Lf[64];

    int t = blockIdx.x;
    int h, qb, half, nkb = 0, kbase = 0, pidx = -1;
    if (t < 288) {
        h = t & 7;
        int rest = t >> 3;             // 0..35 = qbh*6 + half*3 + chunk
        int qbh = rest / 6, r2 = rest % 6;
        half = r2 / 3;
        int chunk = r2 % 3;
        qb = 30 + qbh; nkb = 12; kbase = chunk * 12; pidx = t;
    } else {
        int t2 = t - 288;
        h = t2 & 7;
        int rest = t2 >> 3;            // 0..59 = qb*2 + half
        qb = rest >> 1; half = rest & 1;
    }

    int tid = threadIdx.x, wave = tid >> 6, lane = tid & 63;
    int m16 = lane & 15, quad = lane >> 4;
    int rh = wave & 1, th = wave >> 1;

    constexpr float kScale = 0.08838834764831845f * 1.4426950408889634f;

    // Q A-frags: 2 row-groups per wave (rows rh*32 + rg*16 + m16), pre-scaled
    half8 aq[2][4];
#pragma unroll
    for (int rg = 0; rg < 2; ++rg) {
        int qrow_frag = qb * 128 + half * 64 + rh * 32 + rg * 16 + m16;
        const float* qrp = q + ((size_t)orig_pos(qrow_frag) * 8 + h) * 128;
#pragma unroll
        for (int kc = 0; kc < 4; ++kc) {
            float4v x0 = *reinterpret_cast<const float4v*>(qrp + kc * 32 + quad * 8);
            float4v x1 = *reinterpret_cast<const float4v*>(qrp + kc * 32 + quad * 8 + 4);
#pragma unroll
            for (int j = 0; j < 4; ++j) {
                aq[rg][kc][j]     = (_Float16)(x0[j] * kScale);
                aq[rg][kc][4 + j] = (_Float16)(x1[j] * kScale);
            }
        }
    }

    // fused selection (light tasks only; wave 0) — identical arithmetic
    if (pidx < 0 && wave == 0) {
        float s = -1e30f;
        if (lane < 36) {
            const float4v* qv = (const float4v*)(qp + (h * 36 + qb) * 128);
            const float4v* kv = (const float4v*)(kp + (h * 36 + lane) * 128);
            float acc = 0.f;
            for (int i = 0; i < 32; ++i) {
                float4v a = qv[i], b = kv[i];
                acc += a[0] * b[0] + a[1] * b[1] + a[2] * b[2] + a[3] * b[3];
            }
            s = acc;
        }
        float tmp = s;
        float thr = 0.f;
        for (int i = 0; i < 4; ++i) {
            float mx = tmp;
            for (int off = 1; off < 64; off <<= 1) mx = fmaxf(mx, __shfl_xor(mx, off));
            thr = mx;
            unsigned long long bal = __ballot(tmp == mx);
            int low = __ffsll(bal) - 1;
            if (lane == low) tmp = -3e38f;
        }
        bool keep = (lane < 36) && ((s >= thr) || (lane >= 30));
        unsigned long long mk = __ballot(keep);
        if (lane == 0) Ls[0] = __popcll(mk);
        if (keep) {
            int pos = __popcll(mk & ((1ull << lane) - 1ull));
            Ls[1 + pos] = lane;
        }
    }
    __syncthreads();
    if (pidx < 0) nkb = Ls[0];

    float l_r[2][4];
    float4v o[2][8];
#pragma unroll
    for (int rg = 0; rg < 2; ++rg) {
#pragma unroll
        for (int r = 0; r < 4; ++r) l_r[rg][r] = 0.f;
#pragma unroll
        for (int dt = 0; dt < 8; ++dt) { o[rg][dt][0] = 0.f; o[rg][dt][1] = 0.f; o[rg][dt][2] = 0.f; o[rg][dt][3] = 0.f; }
    }

    short* Phw = Ph + wave * (32 * PPROW);

    int ntile = nkb * 2;
    for (int it = 0; it < ntile; ++it) {
        int kb  = (pidx >= 0) ? (kbase + (it >> 1)) : Ls[1 + (it >> 1)];
        int sub = it & 1;
        const char* gK = (const char*)(Kc + ((size_t)((h * 36 + kb) * 128) + sub * 64) * KROW);
        const char* gV = (const char*)(Vt + (size_t)((h * 36 + kb) * 2 + sub) * 128 * VROW);

        __syncthreads();
        {   // 35 x 1KB chunks (17 K + 18 V)
            char* lK = (char*)Ks;
            char* lV = (char*)Vsh;
            int off = lane * 16;
            for (int c = wave; c < 35; c += 4) {
                if (c < 17) cp16(gK + c * 1024 + off, lK + c * 1024 + off);
                else        cp16(gV + (c - 17) * 1024 + off, lV + (c - 17) * 1024 + off);
            }
        }
        __syncthreads();

        // S = Q K^T (this wave's 32 tokens; bk shared across 2 row-groups)
        float4v sacc[2][2];
#pragma unroll
        for (int rg = 0; rg < 2; ++rg)
#pragma unroll
            for (int nt = 0; nt < 2; ++nt) { sacc[rg][nt][0] = 0.f; sacc[rg][nt][1] = 0.f; sacc[rg][nt][2] = 0.f; sacc[rg][nt][3] = 0.f; }
#pragma unroll
        for (int nt = 0; nt < 2; ++nt)
#pragma unroll
            for (int kc = 0; kc < 4; ++kc) {
                half8 bk = *reinterpret_cast<const half8*>(&Ks[(th * 32 + nt * 16 + m16) * KROW + kc * 32 + quad * 8]);
                sacc[0][nt] = __builtin_amdgcn_mfma_f32_16x16x32_f16(aq[0][kc], bk, sacc[0][nt], 0, 0, 0);
                sacc[1][nt] = __builtin_amdgcn_mfma_f32_16x16x32_f16(aq[1][kc], bk, sacc[1][nt], 0, 0, 0);
            }

        // fixed-m softmax: p = 2^s (scale pre-folded into Q); lane-local l accum
#pragma unroll
        for (int rg = 0; rg < 2; ++rg)
#pragma unroll
            for (int r = 0; r < 4; ++r) {
                float p0 = exp2f(sacc[rg][0][r]);
                float p1 = exp2f(sacc[rg][1][r]);
                sacc[rg][0][r] = p0; sacc[rg][1][r] = p1;
                l_r[rg][r] += p0 + p1;
            }

        // P -> fp16 LDS (wave-private; C-layout write, A-layout read; local 32 cols)
#pragma unroll
        for (int rg = 0; rg < 2; ++rg)
#pragma unroll
            for (int nt = 0; nt < 2; ++nt)
#pragma unroll
                for (int r = 0; r < 4; ++r) {
                    union { _Float16 hf; short s; } cv;
                    cv.hf = (_Float16)sacc[rg][nt][r];
                    Phw[(rg * 16 + quad * 4 + r) * PPROW + nt * 16 + m16] = cv.s;
                }
        half8 ap[2];
#pragma unroll
        for (int rg = 0; rg < 2; ++rg)
            ap[rg] = *reinterpret_cast<const half8*>(&Phw[(rg * 16 + m16) * PPROW + quad * 8]);

        // O += P V over this wave's 32 tokens (bv shared across 2 row-groups)
#pragma unroll
        for (int dt = 0; dt < 8; ++dt) {
            half8 bv = *reinterpret_cast<const half8*>(&Vsh[(dt * 16 + m16) * VROW + th * 32 + quad * 8]);
            o[0][dt] = __builtin_amdgcn_mfma_f32_16x16x32_f16(ap[0], bv, o[0][dt], 0, 0, 0);
            o[1][dt] = __builtin_amdgcn_mfma_f32_16x16x32_f16(ap[1], bv, o[1][dt], 0, 0, 0);
        }
    }

    // reduce l across the 16 cols held per lane-group
#pragma unroll
    for (int rg = 0; rg < 2; ++rg)
#pragma unroll
        for (int r = 0; r < 4; ++r)
            for (int sh = 1; sh < 16; sh <<= 1) l_r[rg][r] += __shfl_xor(l_r[rg][r], sh);

    // cross-wave reduction over token halves (th=1 -> LDS, th=0 adds + writes out)
    __syncthreads();   // all waves done with Ks/Vsh
    {
        float* red = rh ? (float*)Vsh : (float*)Ks;   // 32 rows x stride 132 floats = 16896B
        if (th == 1) {
#pragma unroll
            for (int rg = 0; rg < 2; ++rg) {
#pragma unroll
                for (int dt = 0; dt < 8; ++dt)
#pragma unroll
                    for (int r = 0; r < 4; ++r)
                        red[(rg * 16 + quad * 4 + r) * 132 + dt * 16 + m16] = o[rg][dt][r];
                if (m16 == 0)
#pragma unroll
                    for (int r = 0; r < 4; ++r)
                        Lf[rh * 32 + rg * 16 + quad * 4 + r] = l_r[rg][r];
            }
        }
        __syncthreads();
        if (th == 0) {
#pragma unroll
            for (int rg = 0; rg < 2; ++rg)
#pragma unroll
                for (int dt = 0; dt < 8; ++dt)
#pragma unroll
                    for (int r = 0; r < 4; ++r)
                        o[rg][dt][r] += red[(rg * 16 + quad * 4 + r) * 132 + dt * 16 + m16];

            if (pidx >= 0) {
                float* po = pO + (size_t)pidx * 8192;
#pragma unroll
                for (int rg = 0; rg < 2; ++rg)
#pragma unroll
                    for (int r = 0; r < 4; ++r) {
                        int row = rh * 32 + rg * 16 + quad * 4 + r;
                        float lt2 = l_r[rg][r] + Lf[row];
#pragma unroll
                        for (int dt = 0; dt < 8; ++dt)
                            po[row * 128 + dt * 16 + m16] = o[rg][dt][r];
                        if (m16 == 0) pL[pidx * 64 + row] = lt2;
                    }
            } else {
#pragma unroll
                for (int rg = 0; rg < 2; ++rg)
#pragma unroll
                    for (int r = 0; r < 4; ++r) {
                        int row = rh * 32 + rg * 16 + quad * 4 + r;
                        int qrow = qb * 128 + half * 64 + row;
                        size_t base = ((size_t)orig_pos(qrow) * 8 + h) * 128;
                        float inv = 1.f / (l_r[rg][r] + Lf[row]);
#pragma unroll
                        for (int dt = 0; dt < 8; ++dt)
                            out[base + dt * 16 + m16] = o[rg][dt][r] * inv;
                    }
            }
        }
    }
}

// ---------------- combine (heavy only; fixed-m partials sum linearly) ----------------
__global__ void combine_kernel(const float* __restrict__ pO, const float* __restrict__ pL,
                               float* __restrict__ out) {
    int gb = blockIdx.x;             // 768
    int g  = gb >> 3;                // 96 = (h,qbh,half)
    int rg = gb & 7;                 // row-group: 8 rows each
    int h    = g / 12;
    int rem  = g % 12;
    int qbh  = rem >> 1;
    int half = rem & 1;
    int qb   = 30 + qbh;
    int base_t = (qbh * 6 + half * 3) * 8 + h;  // heavy task id for chunk c: base_t + 8*c

    int tid = threadIdx.x;
    int d   = tid & 127;
    int r0  = tid >> 7;
#pragma unroll
    for (int itr = 0; itr < 4; ++itr) {
        int row = rg * 8 + r0 + itr * 2;
        float l = pL[(base_t + 0) * 64 + row] + pL[(base_t + 8) * 64 + row] + pL[(base_t + 16) * 64 + row];
        float acc = pO[(size_t)(base_t + 0) * 8192 + row * 128 + d]
                  + pO[(size_t)(base_t + 8) * 8192 + row * 128 + d]
                  + pO[(size_t)(base_t + 16) * 8192 + row * 128 + d];
        int qrow = qb * 128 + half * 64 + row;
        out[((size_t)orig_pos(qrow) * 8 + h) * 128 + d] = acc / l;
    }
}

extern "C" void kernel_launch(void* const* d_in, const int* in_sizes, int n_in,
                              void* d_out, int out_size, void* d_ws, size_t ws_size,
                              hipStream_t stream) {
    const float* q = (const float*)d_in[0];
    const float* k = (const float*)d_in[1];
    const float* v = (const float*)d_in[2];
    float* out = (float*)d_out;

    char* w = (char*)d_ws;
    short* Kc  = (short*)(w);                 // 10,027,008 B
    short* Vt  = (short*)(w + 10027008);      // 10,616,832 B (VROW=72)
    float* qp  = (float*)(w + 20643840);      // 147,456 B
    float* kp  = (float*)(w + 20791296);      // 147,456 B
    float* pL  = (float*)(w + 20938752);      // 73,728 B
    float* pO  = (float*)(w + 21012480);      // 9,437,184 B  (total ~30.5 MB)

    prep_kernel<<<dim3(1152), dim3(256), 0, stream>>>(q, k, v, Kc, (unsigned*)Vt, qp, kp);
    flash_kernel<<<dim3(768), dim3(256), 0, stream>>>(q, Kc, Vt, qp, kp, out, pO, pL);
    combine_kernel<<<dim3(768), dim3(256), 0, stream>>>(pO, pL, out);
}